// Round 2
// baseline (1219.369 us; speedup 1.0000x reference)
//
#include <hip/hip_runtime.h>
#include <hip/hip_bf16.h>

#define N_PIX 16384
#define W_ 128

typedef __attribute__((ext_vector_type(8))) unsigned short ushort8_t;

__device__ inline float bf2f(unsigned short u) {
    return __uint_as_float(((unsigned)u) << 16);
}

// ---------------------------------------------------------------------------
// conv1x1 as GEMM (fp32 in, fp32 out): out[o][p] = sum_i w[o][i] * in[i][p]
// one batch per launch. tile 64o x 128p, 256 threads, 4o x 8p micro-tile.
// ---------------------------------------------------------------------------
#define BLK_P 128
#define KC 16

__global__ __launch_bounds__(256) void k_conv1x1(
    const float* __restrict__ in, const float* __restrict__ w,
    float* __restrict__ out, int IC)
{
    const int p0 = blockIdx.x * BLK_P;
    const int o0 = blockIdx.y * 64;

    __shared__ float xs[KC][BLK_P];
    __shared__ float wsh[KC][64];

    const int tid = threadIdx.x;
    const int px = tid & 15;
    const int oy = tid >> 4;

    float acc[4][8];
    #pragma unroll
    for (int i = 0; i < 4; i++)
        #pragma unroll
        for (int j = 0; j < 8; j++) acc[i][j] = 0.f;

    for (int k0 = 0; k0 < IC; k0 += KC) {
        #pragma unroll
        for (int r = 0; r < 2; r++) {
            int idx = tid + r * 256;
            int kk = idx >> 5;
            int pp = (idx & 31) << 2;
            *(float4*)&xs[kk][pp] =
                *(const float4*)(in + (long)(k0 + kk) * N_PIX + p0 + pp);
        }
        {
            int oo = tid >> 2;
            int kq = (tid & 3) << 2;
            float4 v = *(const float4*)(w + (long)(o0 + oo) * IC + k0 + kq);
            wsh[kq + 0][oo] = v.x; wsh[kq + 1][oo] = v.y;
            wsh[kq + 2][oo] = v.z; wsh[kq + 3][oo] = v.w;
        }
        __syncthreads();
        #pragma unroll
        for (int kk = 0; kk < KC; kk++) {
            float xv[8], wv[4];
            *(float4*)&xv[0] = *(float4*)&xs[kk][px * 8];
            *(float4*)&xv[4] = *(float4*)&xs[kk][px * 8 + 4];
            *(float4*)&wv[0] = *(float4*)&wsh[kk][oy * 4];
            #pragma unroll
            for (int i = 0; i < 4; i++)
                #pragma unroll
                for (int j = 0; j < 8; j++)
                    acc[i][j] = fmaf(wv[i], xv[j], acc[i][j]);
        }
        __syncthreads();
    }
    #pragma unroll
    for (int i = 0; i < 4; i++) {
        float* op = out + (long)(o0 + oy * 4 + i) * N_PIX + p0 + px * 8;
        *(float4*)op       = *(float4*)&acc[i][0];
        *(float4*)(op + 4) = *(float4*)&acc[i][4];
    }
}

// ---------------------------------------------------------------------------
// depthwise 3x3, pad 1, fp32 in -> bf16 out. one batch per launch.
// grid: (64 row-pairs, 576 channels), 256 threads = 2 rows x 128 cols
// ---------------------------------------------------------------------------
__global__ __launch_bounds__(256) void k_dwconv(
    const float* __restrict__ in, const float* __restrict__ w,
    __hip_bfloat16* __restrict__ out)
{
    const int ch = blockIdx.y;
    const int y  = blockIdx.x * 2 + (threadIdx.x >> 7);
    const int x  = threadIdx.x & 127;
    const float* wp = w + ch * 9;
    const float* ip = in + (long)ch * N_PIX;
    float s = 0.f;
    #pragma unroll
    for (int ky = 0; ky < 3; ky++) {
        int yy = y + ky - 1;
        if ((unsigned)yy > 127u) continue;
        #pragma unroll
        for (int kx = 0; kx < 3; kx++) {
            int xx = x + kx - 1;
            if ((unsigned)xx > 127u) continue;
            s = fmaf(wp[ky * 3 + kx], ip[yy * W_ + xx], s);
        }
    }
    out[(long)ch * N_PIX + y * W_ + x] = __float2bfloat16(s);
}

// ---------------------------------------------------------------------------
// gram + norms from bf16 qkv:
//   S[attn][bh][c][d] = sum_n q[c,n]*k[d,n]; qn = sum q^2; kn = sum k^2
// attn0: q = x_q, k = ctx_k ; attn1: q = ctx_q, k = x_k
// grid (16 n-chunks, 16 bh, 2 attn), block 64, 6x6 micro-tile, atomic reduce.
// ---------------------------------------------------------------------------
#define GCH 1024
__global__ __launch_bounds__(64) void k_gram(
    const unsigned short* __restrict__ qkv_x,
    const unsigned short* __restrict__ qkv_c,
    float* __restrict__ S, float* __restrict__ qn, float* __restrict__ kn)
{
    const int attn = blockIdx.z;
    const int bh   = blockIdx.y;
    const int b = bh >> 2, h = bh & 3;
    const unsigned short* qb =
        (attn == 0 ? qkv_x : qkv_c) + ((long)b * 576 + h * 48) * N_PIX;
    const unsigned short* kb =
        (attn == 0 ? qkv_c : qkv_x) + ((long)b * 576 + 192 + h * 48) * N_PIX;
    const int n0 = blockIdx.x * GCH;

    __shared__ float qs[64][50];
    __shared__ float ks[64][50];

    const int tid = threadIdx.x;
    const int c0 = (tid >> 3) * 6;
    const int d0 = (tid & 7) * 6;

    float acc[6][6];
    float nq2[6], nk2[6];
    #pragma unroll
    for (int i = 0; i < 6; i++) {
        nq2[i] = 0.f; nk2[i] = 0.f;
        #pragma unroll
        for (int j = 0; j < 6; j++) acc[i][j] = 0.f;
    }

    for (int s = 0; s < GCH / 64; s++) {
        const int ns = n0 + s * 64;
        __syncthreads();
        #pragma unroll
        for (int it = 0; it < 6; it++) {
            int idx = it * 64 + tid;       // 384 octet-loads per tensor
            int c = idx >> 3, no = idx & 7;
            ushort8_t v = *(const ushort8_t*)(qb + (long)c * N_PIX + ns + no * 8);
            #pragma unroll
            for (int j = 0; j < 8; j++) qs[no * 8 + j][c] = bf2f(v[j]);
            ushort8_t u = *(const ushort8_t*)(kb + (long)c * N_PIX + ns + no * 8);
            #pragma unroll
            for (int j = 0; j < 8; j++) ks[no * 8 + j][c] = bf2f(u[j]);
        }
        __syncthreads();
        for (int nn = 0; nn < 64; nn++) {
            float qv[6], kv[6];
            *(float2*)&qv[0] = *(float2*)&qs[nn][c0];
            *(float2*)&qv[2] = *(float2*)&qs[nn][c0 + 2];
            *(float2*)&qv[4] = *(float2*)&qs[nn][c0 + 4];
            *(float2*)&kv[0] = *(float2*)&ks[nn][d0];
            *(float2*)&kv[2] = *(float2*)&ks[nn][d0 + 2];
            *(float2*)&kv[4] = *(float2*)&ks[nn][d0 + 4];
            #pragma unroll
            for (int i = 0; i < 6; i++) {
                nq2[i] = fmaf(qv[i], qv[i], nq2[i]);
                nk2[i] = fmaf(kv[i], kv[i], nk2[i]);
                #pragma unroll
                for (int j = 0; j < 6; j++)
                    acc[i][j] = fmaf(qv[i], kv[j], acc[i][j]);
            }
        }
    }
    float* Sp = S + ((long)(attn * 16 + bh) * 48) * 48;
    #pragma unroll
    for (int i = 0; i < 6; i++)
        #pragma unroll
        for (int j = 0; j < 6; j++)
            atomicAdd(&Sp[(c0 + i) * 48 + d0 + j], acc[i][j]);
    if ((tid & 7) == 0) {
        float* qp = qn + (long)(attn * 16 + bh) * 48;
        #pragma unroll
        for (int i = 0; i < 6; i++) atomicAdd(&qp[c0 + i], nq2[i]);
    }
    if ((tid >> 3) == 0) {
        float* kp = kn + (long)(attn * 16 + bh) * 48;
        #pragma unroll
        for (int i = 0; i < 6; i++) atomicAdd(&kp[d0 + i], nk2[i]);
    }
}

// ---------------------------------------------------------------------------
// softmax: P[attn][b][h][c][d] = softmax_d( S/(|q_c||k_d|) * temp[h] )
// ---------------------------------------------------------------------------
__global__ __launch_bounds__(192) void k_softmax(
    const float* __restrict__ S, const float* __restrict__ qn,
    const float* __restrict__ kn, const float* __restrict__ temp,
    float* __restrict__ P)
{
    const int attn = blockIdx.x, b = blockIdx.y;
    const int r = threadIdx.x;
    const int h = r / 48, c = r % 48;
    const int bh = b * 4 + h;
    const float t = temp[h];
    const float* Srow = S + ((long)(attn * 16 + bh) * 48 + c) * 48;
    const float* knp  = kn + (long)(attn * 16 + bh) * 48;
    const float qc = fmaxf(sqrtf(qn[(long)(attn * 16 + bh) * 48 + c]), 1e-12f);
    float lg[48];
    float mx = -1e30f;
    #pragma unroll
    for (int d = 0; d < 48; d++) {
        float kd = fmaxf(sqrtf(knp[d]), 1e-12f);
        lg[d] = Srow[d] / (qc * kd) * t;
        mx = fmaxf(mx, lg[d]);
    }
    float sum = 0.f;
    #pragma unroll
    for (int d = 0; d < 48; d++) { lg[d] = __expf(lg[d] - mx); sum += lg[d]; }
    const float inv = 1.f / sum;
    float* Pp = P + (((long)(attn * 4 + b) * 4 + h) * 48 + c) * 48;
    #pragma unroll
    for (int d = 0; d < 48; d++) Pp[d] = lg[d] * inv;
}

// ---------------------------------------------------------------------------
// W2[attn][b][o][h*48+d] = sum_c po[o][h*48+c] * P[attn][b][h][c][d]
// attn0 -> ctx_po_w, attn1 -> x_po_w
// ---------------------------------------------------------------------------
__global__ __launch_bounds__(192) void k_w2(
    const float* __restrict__ P, const float* __restrict__ x_po,
    const float* __restrict__ ctx_po, float* __restrict__ W2)
{
    const int h = blockIdx.x, b = blockIdx.y, attn = blockIdx.z;
    const float* po = (attn == 0) ? ctx_po : x_po;
    __shared__ float Pl[48][48];
    const float* Pp = P + ((long)(attn * 4 + b) * 4 + h) * 2304;
    for (int it = 0; it < 12; it++) {
        int idx = it * 192 + threadIdx.x;
        Pl[idx / 48][idx % 48] = Pp[idx];
    }
    __syncthreads();
    const int o = threadIdx.x;
    float acc[48];
    #pragma unroll
    for (int d = 0; d < 48; d++) acc[d] = 0.f;
    for (int c = 0; c < 48; c++) {
        float pv = po[(long)o * 192 + h * 48 + c];
        #pragma unroll
        for (int d = 0; d < 48; d++)
            acc[d] = fmaf(pv, Pl[c][d], acc[d]);
    }
    float* wp = W2 + ((long)(attn * 4 + b) * 192 + o) * 192 + h * 48;
    #pragma unroll
    for (int d = 0; d < 48; d++) wp[d] = acc[d];
}

// ---------------------------------------------------------------------------
// final GEMM: out[o][p] = sum_d W2b[o][d] * v16[d][p]   (bf16 v, fp32 W2/out)
// grid (128, 3, 4=batch); per-batch strides baked in.
// ---------------------------------------------------------------------------
__global__ __launch_bounds__(256) void k_gemm_out(
    const unsigned short* __restrict__ v16,   // + batch*576*N_PIX, v at +384*N_PIX
    const float* __restrict__ w,              // + batch*36864
    float* __restrict__ out)                  // + batch*192*N_PIX
{
    const int p0 = blockIdx.x * BLK_P;
    const int o0 = blockIdx.y * 64;
    const int b  = blockIdx.z;
    const unsigned short* inb = v16 + (long)b * 576 * N_PIX + 384L * N_PIX;
    const float* wb = w + (long)b * 36864;
    float* outb = out + (long)b * 192 * N_PIX;

    __shared__ float xs[KC][BLK_P];
    __shared__ float wsh[KC][64];

    const int tid = threadIdx.x;
    const int px = tid & 15;
    const int oy = tid >> 4;

    float acc[4][8];
    #pragma unroll
    for (int i = 0; i < 4; i++)
        #pragma unroll
        for (int j = 0; j < 8; j++) acc[i][j] = 0.f;

    for (int k0 = 0; k0 < 192; k0 += KC) {
        {   // stage v tile [16][128] from bf16: 256 octet-loads, 1/thread
            int kk = tid >> 4, no = tid & 15;
            ushort8_t v = *(const ushort8_t*)(inb + (long)(k0 + kk) * N_PIX + p0 + no * 8);
            #pragma unroll
            for (int j = 0; j < 8; j++) xs[kk][no * 8 + j] = bf2f(v[j]);
        }
        {
            int oo = tid >> 2;
            int kq = (tid & 3) << 2;
            float4 v = *(const float4*)(wb + (long)(o0 + oo) * 192 + k0 + kq);
            wsh[kq + 0][oo] = v.x; wsh[kq + 1][oo] = v.y;
            wsh[kq + 2][oo] = v.z; wsh[kq + 3][oo] = v.w;
        }
        __syncthreads();
        #pragma unroll
        for (int kk = 0; kk < KC; kk++) {
            float xv[8], wv[4];
            *(float4*)&xv[0] = *(float4*)&xs[kk][px * 8];
            *(float4*)&xv[4] = *(float4*)&xs[kk][px * 8 + 4];
            *(float4*)&wv[0] = *(float4*)&wsh[kk][oy * 4];
            #pragma unroll
            for (int i = 0; i < 4; i++)
                #pragma unroll
                for (int j = 0; j < 8; j++)
                    acc[i][j] = fmaf(wv[i], xv[j], acc[i][j]);
        }
        __syncthreads();
    }
    #pragma unroll
    for (int i = 0; i < 4; i++) {
        float* op = outb + (long)(o0 + oy * 4 + i) * N_PIX + p0 + px * 8;
        *(float4*)op       = *(float4*)&acc[i][0];
        *(float4*)(op + 4) = *(float4*)&acc[i][4];
    }
}

// ---------------------------------------------------------------------------
extern "C" void kernel_launch(void* const* d_in, const int* in_sizes, int n_in,
                              void* d_out, int out_size, void* d_ws, size_t ws_size,
                              hipStream_t stream) {
    (void)in_sizes; (void)n_in; (void)out_size; (void)ws_size;
    const float* x       = (const float*)d_in[0];
    const float* ctx     = (const float*)d_in[1];
    const float* x_qkv_w = (const float*)d_in[2];
    const float* x_dw_w  = (const float*)d_in[3];
    const float* x_po_w  = (const float*)d_in[4];
    const float* c_qkv_w = (const float*)d_in[5];
    const float* c_dw_w  = (const float*)d_in[6];
    const float* c_po_w  = (const float*)d_in[7];
    const float* temp    = (const float*)d_in[8];
    float* out = (float*)d_out;

    // workspace layout (bf16 qkv first, then fp32 stats) — ~153 MB total
    const long QKV = 37748736L;                  // 4*576*16384 elements
    unsigned short* qkv_x16 = (unsigned short*)d_ws;
    unsigned short* qkv_c16 = qkv_x16 + QKV;
    float* S  = (float*)(qkv_c16 + QKV);         // 2*16*48*48 = 73728
    float* qn = S + 73728;                       // 2*16*48
    float* kn = qn + 1536;
    float* P  = kn + 1536;                       // 73728
    float* W2 = P + 73728;                       // 2*4*192*192 = 294912

    hipMemsetAsync(S, 0, (73728 + 1536 + 1536) * sizeof(float), stream);

    // conv tmp lives in d_out (36 MB per step; d_out = 100 MB, fully
    // overwritten by the final GEMMs afterwards)
    float* tmpF = out;

    dim3 blk(256);
    for (int b = 0; b < 4; b++) {
        k_conv1x1<<<dim3(128, 9), blk, 0, stream>>>(
            x + (long)b * 3145728, x_qkv_w, tmpF, 192);
        k_dwconv<<<dim3(64, 576), blk, 0, stream>>>(
            tmpF, x_dw_w, (__hip_bfloat16*)(qkv_x16 + (long)b * 9437184));
    }
    for (int b = 0; b < 4; b++) {
        k_conv1x1<<<dim3(128, 9), blk, 0, stream>>>(
            ctx + (long)b * 3145728, c_qkv_w, tmpF, 192);
        k_dwconv<<<dim3(64, 576), blk, 0, stream>>>(
            tmpF, c_dw_w, (__hip_bfloat16*)(qkv_c16 + (long)b * 9437184));
    }

    k_gram<<<dim3(16, 16, 2), dim3(64), 0, stream>>>(qkv_x16, qkv_c16, S, qn, kn);
    k_softmax<<<dim3(2, 4), dim3(192), 0, stream>>>(S, qn, kn, temp, P);
    k_w2<<<dim3(4, 4, 2), dim3(192), 0, stream>>>(P, x_po_w, c_po_w, W2);

    // x_out = W2[attn1] @ x_v ; ctx_out = W2[attn0] @ ctx_v
    k_gemm_out<<<dim3(128, 3, 4), blk, 0, stream>>>(
        qkv_x16, W2 + 4L * 36864, out);
    k_gemm_out<<<dim3(128, 3, 4), blk, 0, stream>>>(
        qkv_c16, W2, out + 12582912L);
}

// Round 3
// 814.551 us; speedup vs baseline: 1.4970x; 1.4970x over previous
//
#include <hip/hip_runtime.h>
#include <hip/hip_bf16.h>

#define N_PIX 16384
#define W_ 128

typedef __attribute__((ext_vector_type(8))) unsigned short ushort8_t;
typedef __attribute__((ext_vector_type(4))) unsigned short ushort4_t;
typedef __attribute__((ext_vector_type(8))) __bf16 bf16x8;
typedef __attribute__((ext_vector_type(4))) float f32x4;

__device__ inline float bf2f(unsigned short u) {
    return __uint_as_float(((unsigned)u) << 16);
}
__device__ inline unsigned short f2bf(float f) {
    __hip_bfloat16 h = __float2bfloat16(f);
    return *(unsigned short*)&h;
}

// ---------------------------------------------------------------------------
// conv1x1 via bf16 MFMA, x-stationary:
//   out_bf16[b][o][p] = sum_ic w[o][ic] * in[b][ic][p]
// block: 128-p tile, X [128][200] LDS staged once (whole K=192),
// W streamed in 96-row chunks, double-buffered. 4 waves = 2(o) x 2(p),
// wave tile 48o x 64p = 3x4 MFMA tiles, K-step 32.
// ---------------------------------------------------------------------------
__global__ __launch_bounds__(256) void k_conv_mfma(
    const float* __restrict__ in,      // [4][192][N_PIX]
    const float* __restrict__ w,       // [576][192]
    unsigned short* __restrict__ out)  // [4][576][N_PIX] bf16
{
    const int p0 = blockIdx.x * 128;
    const int b  = blockIdx.y;
    const float* inb = in + (long)b * 192 * N_PIX;
    unsigned short* ob = out + (long)b * 576 * N_PIX;

    __shared__ unsigned short Xl[128 * 200];     // 51.2 KB, [p][k] pad 200
    __shared__ unsigned short Wl[2][96 * 200];   // 2 x 38.4 KB

    const int tid  = threadIdx.x;
    const int lane = tid & 63;
    const int wid  = tid >> 6;
    const int wo   = wid >> 1;       // o offset 48*wo
    const int wp   = wid & 1;        // p offset 64*wp
    const int l15  = lane & 15;
    const int lq   = lane >> 4;

    // stage X once: [p][k], transpose from global [k][p]
    {
        const int p = tid & 127, kh = tid >> 7;
        #pragma unroll
        for (int seg = 0; seg < 12; seg++) {
            ushort8_t pk;
            #pragma unroll
            for (int j = 0; j < 8; j++)
                pk[j] = f2bf(inb[(long)(kh * 96 + seg * 8 + j) * N_PIX + p0 + p]);
            *(ushort8_t*)&Xl[p * 200 + kh * 96 + seg * 8] = pk;
        }
    }
    // stage W chunk 0
    #pragma unroll
    for (int it = 0; it < 18; it++) {
        int idx = it * 1024 + tid * 4;
        float4 v = *(const float4*)(w + idx);
        int row = idx / 192, col = idx - row * 192;
        ushort4_t s; s[0] = f2bf(v.x); s[1] = f2bf(v.y); s[2] = f2bf(v.z); s[3] = f2bf(v.w);
        *(ushort4_t*)&Wl[0][row * 200 + col] = s;
    }

    for (int oc = 0; oc < 6; oc++) {
        __syncthreads();
        if (oc + 1 < 6) {   // prefetch next W chunk into other buffer
            const float* wc = w + (long)(oc + 1) * 96 * 192;
            #pragma unroll
            for (int it = 0; it < 18; it++) {
                int idx = it * 1024 + tid * 4;
                float4 v = *(const float4*)(wc + idx);
                int row = idx / 192, col = idx - row * 192;
                ushort4_t s; s[0] = f2bf(v.x); s[1] = f2bf(v.y); s[2] = f2bf(v.z); s[3] = f2bf(v.w);
                *(ushort4_t*)&Wl[(oc + 1) & 1][row * 200 + col] = s;
            }
        }
        const unsigned short* Wb = Wl[oc & 1];
        f32x4 acc[3][4];
        const f32x4 zero = {0.f, 0.f, 0.f, 0.f};
        #pragma unroll
        for (int i = 0; i < 3; i++)
            #pragma unroll
            for (int j = 0; j < 4; j++) acc[i][j] = zero;

        #pragma unroll
        for (int kc = 0; kc < 6; kc++) {
            bf16x8 af[3], bfv[4];
            #pragma unroll
            for (int mt = 0; mt < 3; mt++)
                af[mt] = *(const bf16x8*)&Wb[(wo * 48 + mt * 16 + l15) * 200 + kc * 32 + lq * 8];
            #pragma unroll
            for (int nt = 0; nt < 4; nt++)
                bfv[nt] = *(const bf16x8*)&Xl[(wp * 64 + nt * 16 + l15) * 200 + kc * 32 + lq * 8];
            #pragma unroll
            for (int mt = 0; mt < 3; mt++)
                #pragma unroll
                for (int nt = 0; nt < 4; nt++)
                    acc[mt][nt] = __builtin_amdgcn_mfma_f32_16x16x32_bf16(
                        af[mt], bfv[nt], acc[mt][nt], 0, 0, 0);
        }
        // epilogue: C/D layout row=(lq*4+r) -> o, col=l15 -> p
        #pragma unroll
        for (int mt = 0; mt < 3; mt++) {
            #pragma unroll
            for (int r = 0; r < 4; r++) {
                int o = oc * 96 + wo * 48 + mt * 16 + lq * 4 + r;
                long base = (long)o * N_PIX + p0 + wp * 64 + l15;
                #pragma unroll
                for (int nt = 0; nt < 4; nt++)
                    ob[base + nt * 16] = f2bf(acc[mt][nt][r]);
            }
        }
    }
}

// ---------------------------------------------------------------------------
// depthwise 3x3, pad 1, bf16 in -> bf16 out. grid (64 row-pairs, 2304 maps)
// ---------------------------------------------------------------------------
__global__ __launch_bounds__(256) void k_dwconv(
    const unsigned short* __restrict__ in, const float* __restrict__ w,
    unsigned short* __restrict__ out)
{
    const int m  = blockIdx.y;              // b*576 + ch
    const int ch = m % 576;
    const int y  = blockIdx.x * 2 + (threadIdx.x >> 7);
    const int x  = threadIdx.x & 127;
    const float* wp = w + ch * 9;
    const unsigned short* ip = in + (long)m * N_PIX;
    float s = 0.f;
    #pragma unroll
    for (int ky = 0; ky < 3; ky++) {
        int yy = y + ky - 1;
        if ((unsigned)yy > 127u) continue;
        #pragma unroll
        for (int kx = 0; kx < 3; kx++) {
            int xx = x + kx - 1;
            if ((unsigned)xx > 127u) continue;
            s = fmaf(wp[ky * 3 + kx], bf2f(ip[yy * W_ + xx]), s);
        }
    }
    out[(long)m * N_PIX + y * W_ + x] = f2bf(s);
}

// ---------------------------------------------------------------------------
// gram + norms via MFMA, fragments loaded straight from global (n-contiguous).
//   S[attn][bh] = Q[48,16384] @ K^T ; qn = diag(Q@Q^T), kn = diag(K@K^T)
// grid (16 n-chunks, 16 bh, 2 attn), block 256 = 4 waves x 256 n each.
// ---------------------------------------------------------------------------
__global__ __launch_bounds__(256) void k_gram_mfma(
    const unsigned short* __restrict__ qkv_x,
    const unsigned short* __restrict__ qkv_c,
    float* __restrict__ S, float* __restrict__ qn, float* __restrict__ kn)
{
    const int attn = blockIdx.z;
    const int bh   = blockIdx.y;
    const int b = bh >> 2, h = bh & 3;
    const unsigned short* qb =
        (attn == 0 ? qkv_x : qkv_c) + ((long)b * 576 + h * 48) * N_PIX;
    const unsigned short* kb =
        (attn == 0 ? qkv_c : qkv_x) + ((long)b * 576 + 192 + h * 48) * N_PIX;

    __shared__ float Sl[48 * 49];
    __shared__ float qnl[48], knl[48];

    const int tid = threadIdx.x;
    for (int i = tid; i < 48 * 49; i += 256) Sl[i] = 0.f;
    if (tid < 48) { qnl[tid] = 0.f; knl[tid] = 0.f; }
    __syncthreads();

    const int lane = tid & 63, wid = tid >> 6;
    const int l15 = lane & 15, lq = lane >> 4;
    const long nbase = (long)blockIdx.x * 1024 + wid * 256;

    f32x4 acc[3][3], aq[3], ak[3];
    const f32x4 zero = {0.f, 0.f, 0.f, 0.f};
    #pragma unroll
    for (int i = 0; i < 3; i++) {
        aq[i] = zero; ak[i] = zero;
        #pragma unroll
        for (int j = 0; j < 3; j++) acc[i][j] = zero;
    }

    for (int ks = 0; ks < 8; ks++) {
        const long ns = nbase + ks * 32;
        bf16x8 af[3], bfv[3];
        #pragma unroll
        for (int mt = 0; mt < 3; mt++)
            af[mt] = *(const bf16x8*)(qb + (long)(mt * 16 + l15) * N_PIX + ns + lq * 8);
        #pragma unroll
        for (int nt = 0; nt < 3; nt++)
            bfv[nt] = *(const bf16x8*)(kb + (long)(nt * 16 + l15) * N_PIX + ns + lq * 8);
        #pragma unroll
        for (int mt = 0; mt < 3; mt++)
            #pragma unroll
            for (int nt = 0; nt < 3; nt++)
                acc[mt][nt] = __builtin_amdgcn_mfma_f32_16x16x32_bf16(
                    af[mt], bfv[nt], acc[mt][nt], 0, 0, 0);
        #pragma unroll
        for (int mt = 0; mt < 3; mt++)
            aq[mt] = __builtin_amdgcn_mfma_f32_16x16x32_bf16(af[mt], af[mt], aq[mt], 0, 0, 0);
        #pragma unroll
        for (int nt = 0; nt < 3; nt++)
            ak[nt] = __builtin_amdgcn_mfma_f32_16x16x32_bf16(bfv[nt], bfv[nt], ak[nt], 0, 0, 0);
    }

    // block-level LDS reduce
    #pragma unroll
    for (int mt = 0; mt < 3; mt++)
        #pragma unroll
        for (int nt = 0; nt < 3; nt++)
            #pragma unroll
            for (int r = 0; r < 4; r++)
                atomicAdd(&Sl[(mt * 16 + lq * 4 + r) * 49 + nt * 16 + l15],
                          acc[mt][nt][r]);
    #pragma unroll
    for (int mt = 0; mt < 3; mt++)
        #pragma unroll
        for (int r = 0; r < 4; r++)
            if (l15 == lq * 4 + r) {
                atomicAdd(&qnl[mt * 16 + l15], aq[mt][r]);
                atomicAdd(&knl[mt * 16 + l15], ak[mt][r]);
            }
    __syncthreads();

    float* Sg = S + (long)(attn * 16 + bh) * 2304;
    float* qg = qn + (long)(attn * 16 + bh) * 48;
    float* kg = kn + (long)(attn * 16 + bh) * 48;
    for (int i = tid; i < 2304; i += 256) {
        int row = i / 48, col = i - row * 48;
        atomicAdd(&Sg[i], Sl[row * 49 + col]);
    }
    if (tid < 48) atomicAdd(&qg[tid], qnl[tid]);
    else if (tid < 96) atomicAdd(&kg[tid - 48], knl[tid - 48]);
}

// ---------------------------------------------------------------------------
// softmax: P[attn][b][h][c][d] = softmax_d( S/(|q_c||k_d|) * temp[h] )
// ---------------------------------------------------------------------------
__global__ __launch_bounds__(192) void k_softmax(
    const float* __restrict__ S, const float* __restrict__ qn,
    const float* __restrict__ kn, const float* __restrict__ temp,
    float* __restrict__ P)
{
    const int attn = blockIdx.x, b = blockIdx.y;
    const int r = threadIdx.x;
    const int h = r / 48, c = r % 48;
    const int bh = b * 4 + h;
    const float t = temp[h];
    const float* Srow = S + ((long)(attn * 16 + bh) * 48 + c) * 48;
    const float* knp  = kn + (long)(attn * 16 + bh) * 48;
    const float qc = fmaxf(sqrtf(qn[(long)(attn * 16 + bh) * 48 + c]), 1e-12f);
    float lg[48];
    float mx = -1e30f;
    #pragma unroll
    for (int d = 0; d < 48; d++) {
        float kd = fmaxf(sqrtf(knp[d]), 1e-12f);
        lg[d] = Srow[d] / (qc * kd) * t;
        mx = fmaxf(mx, lg[d]);
    }
    float sum = 0.f;
    #pragma unroll
    for (int d = 0; d < 48; d++) { lg[d] = __expf(lg[d] - mx); sum += lg[d]; }
    const float inv = 1.f / sum;
    float* Pp = P + (((long)(attn * 4 + b) * 4 + h) * 48 + c) * 48;
    #pragma unroll
    for (int d = 0; d < 48; d++) Pp[d] = lg[d] * inv;
}

// ---------------------------------------------------------------------------
// W2[attn][b][o][h*48+d] = sum_c po[o][h*48+c] * P[attn][b][h][c][d]
// ---------------------------------------------------------------------------
__global__ __launch_bounds__(192) void k_w2(
    const float* __restrict__ P, const float* __restrict__ x_po,
    const float* __restrict__ ctx_po, float* __restrict__ W2)
{
    const int h = blockIdx.x, b = blockIdx.y, attn = blockIdx.z;
    const float* po = (attn == 0) ? ctx_po : x_po;
    __shared__ float Pl[48][48];
    const float* Pp = P + ((long)(attn * 4 + b) * 4 + h) * 2304;
    for (int it = 0; it < 12; it++) {
        int idx = it * 192 + threadIdx.x;
        Pl[idx / 48][idx % 48] = Pp[idx];
    }
    __syncthreads();
    const int o = threadIdx.x;
    float acc[48];
    #pragma unroll
    for (int d = 0; d < 48; d++) acc[d] = 0.f;
    for (int c = 0; c < 48; c++) {
        float pv = po[(long)o * 192 + h * 48 + c];
        #pragma unroll
        for (int d = 0; d < 48; d++)
            acc[d] = fmaf(pv, Pl[c][d], acc[d]);
    }
    float* wp = W2 + ((long)(attn * 4 + b) * 192 + o) * 192 + h * 48;
    #pragma unroll
    for (int d = 0; d < 48; d++) wp[d] = acc[d];
}

// ---------------------------------------------------------------------------
// final GEMM: out[o][p] = sum_d W2b[o][d] * v16[d][p]   (bf16 v, fp32 W2/out)
// ---------------------------------------------------------------------------
#define BLK_P 128
#define KC 16
__global__ __launch_bounds__(256) void k_gemm_out(
    const unsigned short* __restrict__ v16,
    const float* __restrict__ w,
    float* __restrict__ out)
{
    const int p0 = blockIdx.x * BLK_P;
    const int o0 = blockIdx.y * 64;
    const int b  = blockIdx.z;
    const unsigned short* inb = v16 + (long)b * 576 * N_PIX + 384L * N_PIX;
    const float* wb = w + (long)b * 36864;
    float* outb = out + (long)b * 192 * N_PIX;

    __shared__ float xs[KC][BLK_P];
    __shared__ float wsh[KC][64];

    const int tid = threadIdx.x;
    const int px = tid & 15;
    const int oy = tid >> 4;

    float acc[4][8];
    #pragma unroll
    for (int i = 0; i < 4; i++)
        #pragma unroll
        for (int j = 0; j < 8; j++) acc[i][j] = 0.f;

    for (int k0 = 0; k0 < 192; k0 += KC) {
        {
            int kk = tid >> 4, no = tid & 15;
            ushort8_t v = *(const ushort8_t*)(inb + (long)(k0 + kk) * N_PIX + p0 + no * 8);
            #pragma unroll
            for (int j = 0; j < 8; j++) xs[kk][no * 8 + j] = bf2f(v[j]);
        }
        {
            int oo = tid >> 2;
            int kq = (tid & 3) << 2;
            float4 v = *(const float4*)(wb + (long)(o0 + oo) * 192 + k0 + kq);
            wsh[kq + 0][oo] = v.x; wsh[kq + 1][oo] = v.y;
            wsh[kq + 2][oo] = v.z; wsh[kq + 3][oo] = v.w;
        }
        __syncthreads();
        #pragma unroll
        for (int kk = 0; kk < KC; kk++) {
            float xv[8], wv[4];
            *(float4*)&xv[0] = *(float4*)&xs[kk][px * 8];
            *(float4*)&xv[4] = *(float4*)&xs[kk][px * 8 + 4];
            *(float4*)&wv[0] = *(float4*)&wsh[kk][oy * 4];
            #pragma unroll
            for (int i = 0; i < 4; i++)
                #pragma unroll
                for (int j = 0; j < 8; j++)
                    acc[i][j] = fmaf(wv[i], xv[j], acc[i][j]);
        }
        __syncthreads();
    }
    #pragma unroll
    for (int i = 0; i < 4; i++) {
        float* op = outb + (long)(o0 + oy * 4 + i) * N_PIX + p0 + px * 8;
        *(float4*)op       = *(float4*)&acc[i][0];
        *(float4*)(op + 4) = *(float4*)&acc[i][4];
    }
}

// ---------------------------------------------------------------------------
extern "C" void kernel_launch(void* const* d_in, const int* in_sizes, int n_in,
                              void* d_out, int out_size, void* d_ws, size_t ws_size,
                              hipStream_t stream) {
    (void)in_sizes; (void)n_in; (void)out_size; (void)ws_size;
    const float* x       = (const float*)d_in[0];
    const float* ctx     = (const float*)d_in[1];
    const float* x_qkv_w = (const float*)d_in[2];
    const float* x_dw_w  = (const float*)d_in[3];
    const float* x_po_w  = (const float*)d_in[4];
    const float* c_qkv_w = (const float*)d_in[5];
    const float* c_dw_w  = (const float*)d_in[6];
    const float* c_po_w  = (const float*)d_in[7];
    const float* temp    = (const float*)d_in[8];
    float* out = (float*)d_out;

    const long QKV = 37748736L;                  // 4*576*16384 elements
    unsigned short* qkv_x16 = (unsigned short*)d_ws;
    unsigned short* qkv_c16 = qkv_x16 + QKV;
    float* S  = (float*)(qkv_c16 + QKV);         // 2*16*48*48
    float* qn = S + 73728;
    float* kn = qn + 1536;
    float* P  = kn + 1536;
    float* W2 = P + 73728;                       // 2*4*192*192

    hipMemsetAsync(S, 0, (73728 + 1536 + 1536) * sizeof(float), stream);

    // conv tmp (bf16) lives in d_out: 75.5 MB < 100.6 MB, fully overwritten
    // by the final GEMMs afterwards.
    unsigned short* tmp16 = (unsigned short*)d_out;

    k_conv_mfma<<<dim3(128, 4), 256, 0, stream>>>(x, x_qkv_w, tmp16);
    k_dwconv<<<dim3(64, 2304), 256, 0, stream>>>(tmp16, x_dw_w, qkv_x16);
    k_conv_mfma<<<dim3(128, 4), 256, 0, stream>>>(ctx, c_qkv_w, tmp16);
    k_dwconv<<<dim3(64, 2304), 256, 0, stream>>>(tmp16, c_dw_w, qkv_c16);

    k_gram_mfma<<<dim3(16, 16, 2), 256, 0, stream>>>(qkv_x16, qkv_c16, S, qn, kn);
    k_softmax<<<dim3(2, 4), dim3(192), 0, stream>>>(S, qn, kn, temp, P);
    k_w2<<<dim3(4, 4, 2), dim3(192), 0, stream>>>(P, x_po_w, c_po_w, W2);

    k_gemm_out<<<dim3(128, 3, 4), 256, 0, stream>>>(qkv_x16, W2 + 4L * 36864, out);
    k_gemm_out<<<dim3(128, 3, 4), 256, 0, stream>>>(qkv_c16, W2, out + 12582912L);
}

// Round 4
// 423.991 us; speedup vs baseline: 2.8759x; 1.9212x over previous
//
#include <hip/hip_runtime.h>
#include <hip/hip_bf16.h>

#define N_PIX 16384
#define W_ 128

typedef __attribute__((ext_vector_type(8))) unsigned short ushort8_t;
typedef __attribute__((ext_vector_type(4))) unsigned short ushort4_t;
typedef __attribute__((ext_vector_type(8))) __bf16 bf16x8;
typedef __attribute__((ext_vector_type(4))) float f32x4;

__device__ inline float bf2f(unsigned short u) {
    return __uint_as_float(((unsigned)u) << 16);
}
__device__ inline unsigned short f2bf(float f) {
    __hip_bfloat16 h = __float2bfloat16(f);
    return *(unsigned short*)&h;
}

// ---------------------------------------------------------------------------
// conv1x1 via bf16 MFMA, x-stationary (unchanged from round 3 — works):
// block: 128-p tile, X [128][200] LDS staged once, W streamed 96-row chunks.
// ---------------------------------------------------------------------------
__global__ __launch_bounds__(256) void k_conv_mfma(
    const float* __restrict__ in,      // [4][192][N_PIX]
    const float* __restrict__ w,       // [576][192]
    unsigned short* __restrict__ out)  // [4][576][N_PIX] bf16
{
    const int p0 = blockIdx.x * 128;
    const int b  = blockIdx.y;
    const float* inb = in + (long)b * 192 * N_PIX;
    unsigned short* ob = out + (long)b * 576 * N_PIX;

    __shared__ unsigned short Xl[128 * 200];
    __shared__ unsigned short Wl[2][96 * 200];

    const int tid  = threadIdx.x;
    const int lane = tid & 63;
    const int wid  = tid >> 6;
    const int wo   = wid >> 1;
    const int wp   = wid & 1;
    const int l15  = lane & 15;
    const int lq   = lane >> 4;

    {
        const int p = tid & 127, kh = tid >> 7;
        #pragma unroll
        for (int seg = 0; seg < 12; seg++) {
            ushort8_t pk;
            #pragma unroll
            for (int j = 0; j < 8; j++)
                pk[j] = f2bf(inb[(long)(kh * 96 + seg * 8 + j) * N_PIX + p0 + p]);
            *(ushort8_t*)&Xl[p * 200 + kh * 96 + seg * 8] = pk;
        }
    }
    #pragma unroll
    for (int it = 0; it < 18; it++) {
        int idx = it * 1024 + tid * 4;
        float4 v = *(const float4*)(w + idx);
        int row = idx / 192, col = idx - row * 192;
        ushort4_t s; s[0] = f2bf(v.x); s[1] = f2bf(v.y); s[2] = f2bf(v.z); s[3] = f2bf(v.w);
        *(ushort4_t*)&Wl[0][row * 200 + col] = s;
    }

    for (int oc = 0; oc < 6; oc++) {
        __syncthreads();
        if (oc + 1 < 6) {
            const float* wc = w + (long)(oc + 1) * 96 * 192;
            #pragma unroll
            for (int it = 0; it < 18; it++) {
                int idx = it * 1024 + tid * 4;
                float4 v = *(const float4*)(wc + idx);
                int row = idx / 192, col = idx - row * 192;
                ushort4_t s; s[0] = f2bf(v.x); s[1] = f2bf(v.y); s[2] = f2bf(v.z); s[3] = f2bf(v.w);
                *(ushort4_t*)&Wl[(oc + 1) & 1][row * 200 + col] = s;
            }
        }
        const unsigned short* Wb = Wl[oc & 1];
        f32x4 acc[3][4];
        const f32x4 zero = {0.f, 0.f, 0.f, 0.f};
        #pragma unroll
        for (int i = 0; i < 3; i++)
            #pragma unroll
            for (int j = 0; j < 4; j++) acc[i][j] = zero;

        #pragma unroll
        for (int kc = 0; kc < 6; kc++) {
            bf16x8 af[3], bfv[4];
            #pragma unroll
            for (int mt = 0; mt < 3; mt++)
                af[mt] = *(const bf16x8*)&Wb[(wo * 48 + mt * 16 + l15) * 200 + kc * 32 + lq * 8];
            #pragma unroll
            for (int nt = 0; nt < 4; nt++)
                bfv[nt] = *(const bf16x8*)&Xl[(wp * 64 + nt * 16 + l15) * 200 + kc * 32 + lq * 8];
            #pragma unroll
            for (int mt = 0; mt < 3; mt++)
                #pragma unroll
                for (int nt = 0; nt < 4; nt++)
                    acc[mt][nt] = __builtin_amdgcn_mfma_f32_16x16x32_bf16(
                        af[mt], bfv[nt], acc[mt][nt], 0, 0, 0);
        }
        #pragma unroll
        for (int mt = 0; mt < 3; mt++) {
            #pragma unroll
            for (int r = 0; r < 4; r++) {
                int o = oc * 96 + wo * 48 + mt * 16 + lq * 4 + r;
                long base = (long)o * N_PIX + p0 + wp * 64 + l15;
                #pragma unroll
                for (int nt = 0; nt < 4; nt++)
                    ob[base + nt * 16] = f2bf(acc[mt][nt][r]);
            }
        }
    }
}

// ---------------------------------------------------------------------------
// depthwise 3x3, pad 1, bf16 -> bf16, vectorized:
// block = 16 rows x 128 cols of one map; 18x128 halo staged in LDS;
// each thread computes 8 contiguous pixels. grid (8 row-groups, 2304 maps).
// ---------------------------------------------------------------------------
__global__ __launch_bounds__(256) void k_dwconv(
    const unsigned short* __restrict__ in, const float* __restrict__ w,
    unsigned short* __restrict__ out)
{
    const int m  = blockIdx.y;              // b*576 + ch
    const int ch = m % 576;
    const int y0 = blockIdx.x * 16;
    const unsigned short* ip = in + (long)m * N_PIX;
    const float* wp = w + ch * 9;

    __shared__ unsigned short Ll[18][136];

    const int tid = threadIdx.x;
    // stage rows y0-1 .. y0+16 (zero-pad out-of-range): 288 ushort8 groups
    #pragma unroll
    for (int idx = tid; idx < 288; idx += 256) {
        int lr = idx >> 4, lc = (idx & 15) * 8;
        int gy = y0 - 1 + lr;
        ushort8_t v;
        #pragma unroll
        for (int j = 0; j < 8; j++) v[j] = 0;
        if ((unsigned)gy <= 127u)
            v = *(const ushort8_t*)(ip + gy * W_ + lc);
        *(ushort8_t*)&Ll[lr][lc] = v;
    }
    float wv[9];
    #pragma unroll
    for (int i = 0; i < 9; i++) wv[i] = wp[i];
    __syncthreads();

    const int r  = tid >> 4;           // output row within group
    const int xg = (tid & 15) * 8;     // first of 8 output cols

    float o[8];
    #pragma unroll
    for (int j = 0; j < 8; j++) o[j] = 0.f;

    #pragma unroll
    for (int dy = 0; dy < 3; dy++) {
        const unsigned short* lrow = &Ll[r + dy][0];
        float c[10];
        c[0] = (xg == 0) ? 0.f : bf2f(lrow[xg - 1]);
        ushort8_t mid = *(const ushort8_t*)&lrow[xg];
        #pragma unroll
        for (int j = 0; j < 8; j++) c[1 + j] = bf2f(mid[j]);
        c[9] = (xg == 120) ? 0.f : bf2f(lrow[xg + 8]);
        const float w0 = wv[dy * 3], w1 = wv[dy * 3 + 1], w2 = wv[dy * 3 + 2];
        #pragma unroll
        for (int j = 0; j < 8; j++)
            o[j] = fmaf(w0, c[j], fmaf(w1, c[j + 1], fmaf(w2, c[j + 2], o[j])));
    }
    ushort8_t res;
    #pragma unroll
    for (int j = 0; j < 8; j++) res[j] = f2bf(o[j]);
    *(ushort8_t*)(out + (long)m * N_PIX + (y0 + r) * W_ + xg) = res;
}

// ---------------------------------------------------------------------------
// gram + norms via MFMA (unchanged from round 3)
// ---------------------------------------------------------------------------
__global__ __launch_bounds__(256) void k_gram_mfma(
    const unsigned short* __restrict__ qkv_x,
    const unsigned short* __restrict__ qkv_c,
    float* __restrict__ S, float* __restrict__ qn, float* __restrict__ kn)
{
    const int attn = blockIdx.z;
    const int bh   = blockIdx.y;
    const int b = bh >> 2, h = bh & 3;
    const unsigned short* qb =
        (attn == 0 ? qkv_x : qkv_c) + ((long)b * 576 + h * 48) * N_PIX;
    const unsigned short* kb =
        (attn == 0 ? qkv_c : qkv_x) + ((long)b * 576 + 192 + h * 48) * N_PIX;

    __shared__ float Sl[48 * 49];
    __shared__ float qnl[48], knl[48];

    const int tid = threadIdx.x;
    for (int i = tid; i < 48 * 49; i += 256) Sl[i] = 0.f;
    if (tid < 48) { qnl[tid] = 0.f; knl[tid] = 0.f; }
    __syncthreads();

    const int lane = tid & 63, wid = tid >> 6;
    const int l15 = lane & 15, lq = lane >> 4;
    const long nbase = (long)blockIdx.x * 1024 + wid * 256;

    f32x4 acc[3][3], aq[3], ak[3];
    const f32x4 zero = {0.f, 0.f, 0.f, 0.f};
    #pragma unroll
    for (int i = 0; i < 3; i++) {
        aq[i] = zero; ak[i] = zero;
        #pragma unroll
        for (int j = 0; j < 3; j++) acc[i][j] = zero;
    }

    for (int ks = 0; ks < 8; ks++) {
        const long ns = nbase + ks * 32;
        bf16x8 af[3], bfv[3];
        #pragma unroll
        for (int mt = 0; mt < 3; mt++)
            af[mt] = *(const bf16x8*)(qb + (long)(mt * 16 + l15) * N_PIX + ns + lq * 8);
        #pragma unroll
        for (int nt = 0; nt < 3; nt++)
            bfv[nt] = *(const bf16x8*)(kb + (long)(nt * 16 + l15) * N_PIX + ns + lq * 8);
        #pragma unroll
        for (int mt = 0; mt < 3; mt++)
            #pragma unroll
            for (int nt = 0; nt < 3; nt++)
                acc[mt][nt] = __builtin_amdgcn_mfma_f32_16x16x32_bf16(
                    af[mt], bfv[nt], acc[mt][nt], 0, 0, 0);
        #pragma unroll
        for (int mt = 0; mt < 3; mt++)
            aq[mt] = __builtin_amdgcn_mfma_f32_16x16x32_bf16(af[mt], af[mt], aq[mt], 0, 0, 0);
        #pragma unroll
        for (int nt = 0; nt < 3; nt++)
            ak[nt] = __builtin_amdgcn_mfma_f32_16x16x32_bf16(bfv[nt], bfv[nt], ak[nt], 0, 0, 0);
    }

    #pragma unroll
    for (int mt = 0; mt < 3; mt++)
        #pragma unroll
        for (int nt = 0; nt < 3; nt++)
            #pragma unroll
            for (int r = 0; r < 4; r++)
                atomicAdd(&Sl[(mt * 16 + lq * 4 + r) * 49 + nt * 16 + l15],
                          acc[mt][nt][r]);
    #pragma unroll
    for (int mt = 0; mt < 3; mt++)
        #pragma unroll
        for (int r = 0; r < 4; r++)
            if (l15 == lq * 4 + r) {
                atomicAdd(&qnl[mt * 16 + l15], aq[mt][r]);
                atomicAdd(&knl[mt * 16 + l15], ak[mt][r]);
            }
    __syncthreads();

    float* Sg = S + (long)(attn * 16 + bh) * 2304;
    float* qg = qn + (long)(attn * 16 + bh) * 48;
    float* kg = kn + (long)(attn * 16 + bh) * 48;
    for (int i = tid; i < 2304; i += 256) {
        int row = i / 48, col = i - row * 48;
        atomicAdd(&Sg[i], Sl[row * 49 + col]);
    }
    if (tid < 48) atomicAdd(&qg[tid], qnl[tid]);
    else if (tid < 96) atomicAdd(&kg[tid - 48], knl[tid - 48]);
}

// ---------------------------------------------------------------------------
// softmax (unchanged)
// ---------------------------------------------------------------------------
__global__ __launch_bounds__(192) void k_softmax(
    const float* __restrict__ S, const float* __restrict__ qn,
    const float* __restrict__ kn, const float* __restrict__ temp,
    float* __restrict__ P)
{
    const int attn = blockIdx.x, b = blockIdx.y;
    const int r = threadIdx.x;
    const int h = r / 48, c = r % 48;
    const int bh = b * 4 + h;
    const float t = temp[h];
    const float* Srow = S + ((long)(attn * 16 + bh) * 48 + c) * 48;
    const float* knp  = kn + (long)(attn * 16 + bh) * 48;
    const float qc = fmaxf(sqrtf(qn[(long)(attn * 16 + bh) * 48 + c]), 1e-12f);
    float lg[48];
    float mx = -1e30f;
    #pragma unroll
    for (int d = 0; d < 48; d++) {
        float kd = fmaxf(sqrtf(knp[d]), 1e-12f);
        lg[d] = Srow[d] / (qc * kd) * t;
        mx = fmaxf(mx, lg[d]);
    }
    float sum = 0.f;
    #pragma unroll
    for (int d = 0; d < 48; d++) { lg[d] = __expf(lg[d] - mx); sum += lg[d]; }
    const float inv = 1.f / sum;
    float* Pp = P + (((long)(attn * 4 + b) * 4 + h) * 48 + c) * 48;
    #pragma unroll
    for (int d = 0; d < 48; d++) Pp[d] = lg[d] * inv;
}

// ---------------------------------------------------------------------------
// W2[attn][b][o][h*48+d] = sum_c po[o][h*48+c] * P[attn][b][h][c][d]
// now writes bf16 for the MFMA final GEMM.
// ---------------------------------------------------------------------------
__global__ __launch_bounds__(192) void k_w2(
    const float* __restrict__ P, const float* __restrict__ x_po,
    const float* __restrict__ ctx_po, unsigned short* __restrict__ W2)
{
    const int h = blockIdx.x, b = blockIdx.y, attn = blockIdx.z;
    const float* po = (attn == 0) ? ctx_po : x_po;
    __shared__ float Pl[48][48];
    const float* Pp = P + ((long)(attn * 4 + b) * 4 + h) * 2304;
    for (int it = 0; it < 12; it++) {
        int idx = it * 192 + threadIdx.x;
        Pl[idx / 48][idx % 48] = Pp[idx];
    }
    __syncthreads();
    const int o = threadIdx.x;
    float acc[48];
    #pragma unroll
    for (int d = 0; d < 48; d++) acc[d] = 0.f;
    for (int c = 0; c < 48; c++) {
        float pv = po[(long)o * 192 + h * 48 + c];
        #pragma unroll
        for (int d = 0; d < 48; d++)
            acc[d] = fmaf(pv, Pl[c][d], acc[d]);
    }
    unsigned short* wp = W2 + ((long)(attn * 4 + b) * 192 + o) * 192 + h * 48;
    #pragma unroll
    for (int d = 0; d < 48; d++) wp[d] = f2bf(acc[d]);
}

// ---------------------------------------------------------------------------
// final GEMM via MFMA: out[br][b][o][p] = sum_d W2bf[.][o][d] * v[d][p]
// br0: x_v with W2[attn1]; br1: ctx_v with W2[attn0]. grid (128, 8)
// ---------------------------------------------------------------------------
__global__ __launch_bounds__(256) void k_gemm_v(
    const unsigned short* __restrict__ qkv_x,
    const unsigned short* __restrict__ qkv_c,
    const unsigned short* __restrict__ W2bf,   // [attn][b][192][192] bf16
    float* __restrict__ out)
{
    const int p0 = blockIdx.x * 128;
    const int z  = blockIdx.y;
    const int br = z >> 2, b = z & 3;
    const unsigned short* v =
        (br == 0 ? qkv_x : qkv_c) + (long)b * 576 * N_PIX + 384L * N_PIX;
    const unsigned short* wb =
        W2bf + ((long)((br == 0 ? 1 : 0) * 4 + b)) * 36864;
    float* ob = out + (long)br * 12582912 + (long)b * 192 * N_PIX;

    __shared__ unsigned short Xl[128 * 200];

    const int tid  = threadIdx.x;
    const int lane = tid & 63;
    const int wid  = tid >> 6;
    const int wo   = wid >> 1;
    const int wp   = wid & 1;
    const int l15  = lane & 15;
    const int lq   = lane >> 4;

    {   // stage V tile transposed [p][k]
        const int p = tid & 127, kh = tid >> 7;
        #pragma unroll
        for (int seg = 0; seg < 12; seg++) {
            ushort8_t pk;
            #pragma unroll
            for (int j = 0; j < 8; j++)
                pk[j] = v[(long)(kh * 96 + seg * 8 + j) * N_PIX + p0 + p];
            *(ushort8_t*)&Xl[p * 200 + kh * 96 + seg * 8] = pk;
        }
    }
    __syncthreads();

    #pragma unroll
    for (int oc = 0; oc < 2; oc++) {
        f32x4 acc[3][4];
        const f32x4 zero = {0.f, 0.f, 0.f, 0.f};
        #pragma unroll
        for (int i = 0; i < 3; i++)
            #pragma unroll
            for (int j = 0; j < 4; j++) acc[i][j] = zero;

        #pragma unroll
        for (int kc = 0; kc < 6; kc++) {
            bf16x8 af[3], bfv[4];
            #pragma unroll
            for (int mt = 0; mt < 3; mt++)
                af[mt] = *(const bf16x8*)(wb +
                    (long)(oc * 96 + wo * 48 + mt * 16 + l15) * 192 + kc * 32 + lq * 8);
            #pragma unroll
            for (int nt = 0; nt < 4; nt++)
                bfv[nt] = *(const bf16x8*)&Xl[(wp * 64 + nt * 16 + l15) * 200 + kc * 32 + lq * 8];
            #pragma unroll
            for (int mt = 0; mt < 3; mt++)
                #pragma unroll
                for (int nt = 0; nt < 4; nt++)
                    acc[mt][nt] = __builtin_amdgcn_mfma_f32_16x16x32_bf16(
                        af[mt], bfv[nt], acc[mt][nt], 0, 0, 0);
        }
        #pragma unroll
        for (int mt = 0; mt < 3; mt++) {
            #pragma unroll
            for (int r = 0; r < 4; r++) {
                int o = oc * 96 + wo * 48 + mt * 16 + lq * 4 + r;
                long base = (long)o * N_PIX + p0 + wp * 64 + l15;
                #pragma unroll
                for (int nt = 0; nt < 4; nt++)
                    ob[base + nt * 16] = acc[mt][nt][r];
            }
        }
    }
}

// ---------------------------------------------------------------------------
extern "C" void kernel_launch(void* const* d_in, const int* in_sizes, int n_in,
                              void* d_out, int out_size, void* d_ws, size_t ws_size,
                              hipStream_t stream) {
    (void)in_sizes; (void)n_in; (void)out_size; (void)ws_size;
    const float* x       = (const float*)d_in[0];
    const float* ctx     = (const float*)d_in[1];
    const float* x_qkv_w = (const float*)d_in[2];
    const float* x_dw_w  = (const float*)d_in[3];
    const float* x_po_w  = (const float*)d_in[4];
    const float* c_qkv_w = (const float*)d_in[5];
    const float* c_dw_w  = (const float*)d_in[6];
    const float* c_po_w  = (const float*)d_in[7];
    const float* temp    = (const float*)d_in[8];
    float* out = (float*)d_out;

    const long QKV = 37748736L;                  // 4*576*16384 elements
    unsigned short* qkv_x16 = (unsigned short*)d_ws;
    unsigned short* qkv_c16 = qkv_x16 + QKV;
    float* S  = (float*)(qkv_c16 + QKV);         // 2*16*48*48
    float* qn = S + 73728;
    float* kn = qn + 1536;
    float* P  = kn + 1536;
    unsigned short* W2bf = (unsigned short*)(P + 73728);   // 2*4*192*192 bf16

    hipMemsetAsync(S, 0, (73728 + 1536 + 1536) * sizeof(float), stream);

    // conv tmp (bf16) lives in d_out: fully overwritten by k_gemm_v afterwards
    unsigned short* tmp16 = (unsigned short*)d_out;

    k_conv_mfma<<<dim3(128, 4), 256, 0, stream>>>(x, x_qkv_w, tmp16);
    k_dwconv<<<dim3(8, 2304), 256, 0, stream>>>(tmp16, x_dw_w, qkv_x16);
    k_conv_mfma<<<dim3(128, 4), 256, 0, stream>>>(ctx, c_qkv_w, tmp16);
    k_dwconv<<<dim3(8, 2304), 256, 0, stream>>>(tmp16, c_dw_w, qkv_c16);

    k_gram_mfma<<<dim3(16, 16, 2), 256, 0, stream>>>(qkv_x16, qkv_c16, S, qn, kn);
    k_softmax<<<dim3(2, 4), dim3(192), 0, stream>>>(S, qn, kn, temp, P);
    k_w2<<<dim3(4, 4, 2), dim3(192), 0, stream>>>(P, x_po_w, c_po_w, W2bf);

    k_gemm_v<<<dim3(128, 8), 256, 0, stream>>>(qkv_x16, qkv_c16, W2bf, out);
}